// Round 12
// baseline (52.752 us; speedup 1.0000x reference)
//
#include <hip/hip_runtime.h>
#include <hip/hip_bf16.h>

// MLP_small_per_feature: per-feature MLP 1 -> 64 -> 64 -> 1, F=256, B=8192.
// v12 = v11's verified math, ONE variable changed: 512-thread blocks
// (8 waves = 4 features x 2 row-groups of 128 rows) to FORCE 8-wave
// co-residency per CU (and 16 waves/CU at VGPR<=128). Rounds 4/7/9 raised
// *available* blocks; none forced stacking. This tests the mechanism.
//
// Carried from v11 (absmax 0.03125):
//  - w2p packed bf16 fragment-major with OUTPUT rows permuted
//    o'(16t+m)=32*(t>>1)+8*(m>>2)+4*(t&1)+(m&3) so layer-2's C/D lands in
//    B-fragment k-slot order; relu+cvt feeds a 3rd MFMA computing layer 3
//    (A = w3 broadcast); b2 in C operand; b3 in layer-3 C operand.
//  - 2-pass ILP pairing; coalesced x staging (pass-major LDS); outb
//    exchange for float4 stores.
// Spill canaries (v5/v6/v8 lessons): SGPR<=48, WRITE_SIZE ~8MB.
//
// MFMA 16x16x32_bf16 layout (verified rounds 1-11):
//   A: row m = lane&15, k = (lane>>4)*8 + i
//   B: col n = lane&15, k = (lane>>4)*8 + i
//   C/D: col n = lane&15, row m = (lane>>4)*4 + r

namespace {

constexpr int kF = 256;
constexpr int kH = 64;
constexpr int kB = 8192;

constexpr int kFPB     = 4;               // features per block
constexpr int kRGI     = 2;               // row-groups per block
constexpr int kRPG     = 128;             // rows per row-group (per wave)
constexpr int kRPB     = kRGI * kRPG;     // 256 rows per block
constexpr int kThreads = 512;             // 8 waves, co-resident by construction
constexpr int kFG      = kF / kFPB;       // 64 feature groups
constexpr int kRG      = kB / kRPB;       // 32 row groups
constexpr int kBlocks  = kFG * kRG;       // 2048
constexpr int kPasses  = kRPG / 16;       // 8
constexpr int kXP      = 10;              // xs pass-dim stride: conflict-free

using f32x2  = __attribute__((ext_vector_type(2))) float;
using f32x4  = __attribute__((ext_vector_type(4))) float;
using bf16x4 = __attribute__((ext_vector_type(4))) __bf16;
using bf16x8 = __attribute__((ext_vector_type(8))) __bf16;

// ---- prep: pack w2 (o'-permuted, bf16, fragment-major), b2 (o'-permuted,
// C-layout order), w3 (bf16). One wave per feature. (verified v10/v11) ----
__global__ __launch_bounds__(256)
void pack_params(const float* __restrict__ w2, const float* __restrict__ b2,
                 const float* __restrict__ w3, __bf16* __restrict__ w2p,
                 float* __restrict__ b2p, __bf16* __restrict__ w3p)
{
  const int wid  = (int)threadIdx.x >> 6;
  const int lane = (int)threadIdx.x & 63;
  const int f    = (int)blockIdx.x * 4 + wid;
  const int l15  = lane & 15;
  const int lg   = lane >> 4;

  const float* w2f = w2 + (size_t)f * (kH * kH);
  #pragma unroll
  for (int t = 0; t < 4; ++t) {
    const int o2 = 32 * (t >> 1) + 8 * (l15 >> 2) + 4 * (t & 1) + (l15 & 3);
    #pragma unroll
    for (int ks = 0; ks < 2; ++ks) {
      const float* p = w2f + o2 * kH + ks * 32 + lg * 8;
      const f32x4 lo = *reinterpret_cast<const f32x4*>(p);
      const f32x4 hi = *reinterpret_cast<const f32x4*>(p + 4);
      const bf16x8 v = __builtin_shufflevector(
          __builtin_convertvector(lo, bf16x4),
          __builtin_convertvector(hi, bf16x4), 0, 1, 2, 3, 4, 5, 6, 7);
      *reinterpret_cast<bf16x8*>(
          w2p + (((size_t)f * 8 + t * 2 + ks) * 64 + lane) * 8) = v;
    }
  }

  {
    const int jt = lane >> 4, jlg = (lane >> 2) & 3, jr = lane & 3;
    const int o  = 32 * (jt >> 1) + 8 * jlg + 4 * (jt & 1) + jr;
    b2p[(size_t)f * kH + lane] = b2[(size_t)f * kH + o];
  }
  w3p[(size_t)f * kH + lane] = (__bf16)w3[(size_t)f * kH + lane];
}

__global__ __launch_bounds__(kThreads, 2)
void mlp_pf_v12(const float* __restrict__ x,
                const float* __restrict__ w1,
                const float* __restrict__ b1,
                const __bf16* __restrict__ w2p,
                const float* __restrict__ b2p,
                const __bf16* __restrict__ w3p,
                const float* __restrict__ b3,
                float* __restrict__ out)
{
  __shared__ float xs[kRGI][kFPB][16][kXP];  // 5 KB [rgi][feat][l15][pass]
  __shared__ float outb[kRPB][kFPB + 1];     // 5.1 KB (pad: conflict-free)

  const int tid  = (int)threadIdx.x;
  const int wid  = tid >> 6;                 // 0..7
  const int wf   = wid & 3;                  // feature slot within block
  const int rgi  = wid >> 2;                 // row-group within block
  const int lane = tid & 63;
  const int l15  = lane & 15;
  const int lg   = lane >> 4;

  const int fg = (int)blockIdx.x & (kFG - 1);
  const int rg = (int)blockIdx.x >> 6;
  const int f  = fg * kFPB + wf;             // this wave's feature
  const int r0 = rg * kRPB;                  // block row base
  const int rw0 = r0 + rgi * kRPG;           // wave row base

  // ---- w2 fragments: 8 coalesced 16B loads/lane (L2-resident w2p) ----
  bf16x8 w2frag[4][2];
  {
    const __bf16* base = w2p + ((size_t)f * 8 * 64 + lane) * 8;
    #pragma unroll
    for (int t = 0; t < 4; ++t)
      #pragma unroll
      for (int ks = 0; ks < 2; ++ks)
        w2frag[t][ks] = *reinterpret_cast<const bf16x8*>(
            base + (size_t)(t * 2 + ks) * 64 * 8);
  }

  // ---- stage x tile (256 rows x 4 feats) -> pass-major LDS ----
  // thread -> row rr = tid>>1, feature half hh = tid&1 (8B coalesced)
  {
    const int rr = tid >> 1, hh = tid & 1;
    const f32x2 v = *reinterpret_cast<const f32x2*>(
        x + (size_t)(r0 + rr) * kF + fg * kFPB + hh * 2);
    const int xrgi = rr >> 7, lr = rr & 127;
    xs[xrgi][hh * 2 + 0][lr & 15][lr >> 4] = v[0];
    xs[xrgi][hh * 2 + 1][lr & 15][lr >> 4] = v[1];
  }

  // ---- per-wave params ----
  f32x4 w1v[2][2], b1v[2][2];
  #pragma unroll
  for (int ks = 0; ks < 2; ++ks) {
    const float* pw = w1 + f * kH + ks * 32 + lg * 8;
    const float* pb = b1 + f * kH + ks * 32 + lg * 8;
    w1v[ks][0] = *reinterpret_cast<const f32x4*>(pw);
    w1v[ks][1] = *reinterpret_cast<const f32x4*>(pw + 4);
    b1v[ks][0] = *reinterpret_cast<const f32x4*>(pb);
    b1v[ks][1] = *reinterpret_cast<const f32x4*>(pb + 4);
  }
  f32x4 b2c[4];
  #pragma unroll
  for (int t = 0; t < 4; ++t)
    b2c[t] = *reinterpret_cast<const f32x4*>(b2p + f * kH + t * 16 + lg * 4);
  bf16x8 w3f[2];
  #pragma unroll
  for (int ks = 0; ks < 2; ++ks)
    w3f[ks] = *reinterpret_cast<const bf16x8*>(w3p + f * kH + ks * 32 + lg * 8);
  const float b3v = b3[f];
  const f32x4 b3c = {b3v, b3v, b3v, b3v};

  __syncthreads();   // xs ready

  const f32x4 zero4 = {0.f, 0.f, 0.f, 0.f};
  float keep = 0.f;

  #pragma unroll
  for (int pp = 0; pp < kPasses / 2; ++pp) {
    const f32x2 xp = *reinterpret_cast<const f32x2*>(&xs[rgi][wf][l15][2 * pp]);

    // ---- layer 1 for both passes (independent chains) ----
    bf16x8 h1A[2], h1B[2];
    #pragma unroll
    for (int ks = 0; ks < 2; ++ks) {
      f32x4 aA = w1v[ks][0] * xp[0] + b1v[ks][0];
      f32x4 bA = w1v[ks][1] * xp[0] + b1v[ks][1];
      f32x4 aB = w1v[ks][0] * xp[1] + b1v[ks][0];
      f32x4 bB = w1v[ks][1] * xp[1] + b1v[ks][1];
      aA = __builtin_elementwise_max(aA, zero4);
      bA = __builtin_elementwise_max(bA, zero4);
      aB = __builtin_elementwise_max(aB, zero4);
      bB = __builtin_elementwise_max(bB, zero4);
      h1A[ks] = __builtin_shufflevector(
          __builtin_convertvector(aA, bf16x4),
          __builtin_convertvector(bA, bf16x4), 0, 1, 2, 3, 4, 5, 6, 7);
      h1B[ks] = __builtin_shufflevector(
          __builtin_convertvector(aB, bf16x4),
          __builtin_convertvector(bB, bf16x4), 0, 1, 2, 3, 4, 5, 6, 7);
    }

    // ---- layer 2 (C = permuted b2), A/B interleaved ----
    f32x4 accA[4], accB[4];
    #pragma unroll
    for (int t = 0; t < 4; ++t) {
      accA[t] = __builtin_amdgcn_mfma_f32_16x16x32_bf16(
          w2frag[t][0], h1A[0], b2c[t], 0, 0, 0);
      accB[t] = __builtin_amdgcn_mfma_f32_16x16x32_bf16(
          w2frag[t][0], h1B[0], b2c[t], 0, 0, 0);
      accA[t] = __builtin_amdgcn_mfma_f32_16x16x32_bf16(
          w2frag[t][1], h1A[1], accA[t], 0, 0, 0);
      accB[t] = __builtin_amdgcn_mfma_f32_16x16x32_bf16(
          w2frag[t][1], h1B[1], accB[t], 0, 0, 0);
    }

    // ---- relu + cvt: acc pairs form B-fragments of the layer-3 MFMA ----
    bf16x8 h2A0, h2A1, h2B0, h2B1;
    {
      const f32x4 rA0 = __builtin_elementwise_max(accA[0], zero4);
      const f32x4 rA1 = __builtin_elementwise_max(accA[1], zero4);
      const f32x4 rA2 = __builtin_elementwise_max(accA[2], zero4);
      const f32x4 rA3 = __builtin_elementwise_max(accA[3], zero4);
      const f32x4 rB0 = __builtin_elementwise_max(accB[0], zero4);
      const f32x4 rB1 = __builtin_elementwise_max(accB[1], zero4);
      const f32x4 rB2 = __builtin_elementwise_max(accB[2], zero4);
      const f32x4 rB3 = __builtin_elementwise_max(accB[3], zero4);
      h2A0 = __builtin_shufflevector(__builtin_convertvector(rA0, bf16x4),
                                     __builtin_convertvector(rA1, bf16x4),
                                     0, 1, 2, 3, 4, 5, 6, 7);
      h2A1 = __builtin_shufflevector(__builtin_convertvector(rA2, bf16x4),
                                     __builtin_convertvector(rA3, bf16x4),
                                     0, 1, 2, 3, 4, 5, 6, 7);
      h2B0 = __builtin_shufflevector(__builtin_convertvector(rB0, bf16x4),
                                     __builtin_convertvector(rB1, bf16x4),
                                     0, 1, 2, 3, 4, 5, 6, 7);
      h2B1 = __builtin_shufflevector(__builtin_convertvector(rB2, bf16x4),
                                     __builtin_convertvector(rB3, bf16x4),
                                     0, 1, 2, 3, 4, 5, 6, 7);
    }

    // ---- layer 3 via MFMA (C = b3 splat) ----
    f32x4 dA = __builtin_amdgcn_mfma_f32_16x16x32_bf16(w3f[0], h2A0, b3c, 0, 0, 0);
    f32x4 dB = __builtin_amdgcn_mfma_f32_16x16x32_bf16(w3f[0], h2B0, b3c, 0, 0, 0);
    dA = __builtin_amdgcn_mfma_f32_16x16x32_bf16(w3f[1], h2A1, dA, 0, 0, 0);
    dB = __builtin_amdgcn_mfma_f32_16x16x32_bf16(w3f[1], h2B1, dB, 0, 0, 0);

    // ---- keep-trick: lane-group lg keeps pass quad*4+lg ----
    const int pA = 2 * pp, pB = 2 * pp + 1;
    keep = (lg == (pA & 3)) ? dA[0] : keep;
    keep = (lg == (pB & 3)) ? dB[0] : keep;
    if ((pB & 3) == 3) {
      outb[rgi * kRPG + (pB >> 2) * 64 + lane][wf] = keep;  // b3 folded in
    }
  }

  __syncthreads();

  // ---- output: one float4 (4 features) per row ----
  if (tid < kRPB) {
    const int rr = tid;
    const f32x4 v = {outb[rr][0], outb[rr][1], outb[rr][2], outb[rr][3]};
    *reinterpret_cast<f32x4*>(out + (size_t)(r0 + rr) * kF + fg * kFPB) = v;
  }
}

}  // namespace

extern "C" void kernel_launch(void* const* d_in, const int* in_sizes, int n_in,
                              void* d_out, int out_size, void* d_ws, size_t ws_size,
                              hipStream_t stream) {
  const float* x  = (const float*)d_in[0];
  const float* w1 = (const float*)d_in[1];
  const float* b1 = (const float*)d_in[2];
  const float* w2 = (const float*)d_in[3];
  const float* b2 = (const float*)d_in[4];
  const float* w3 = (const float*)d_in[5];
  const float* b3 = (const float*)d_in[6];
  float* out = (float*)d_out;

  __bf16* w2p = (__bf16*)d_ws;                           // 2 MB
  float*  b2p = (float*)((char*)d_ws + (2u << 20));      // 64 KB
  __bf16* w3p = (__bf16*)((char*)d_ws + (2u << 20) + (64u << 10));  // 32 KB

  hipLaunchKernelGGL(pack_params, dim3(kF / 4), dim3(256), 0, stream,
                     w2, b2, w3, w2p, b2p, w3p);
  hipLaunchKernelGGL(mlp_pf_v12, dim3(kBlocks), dim3(kThreads), 0, stream,
                     x, w1, b1, w2p, b2p, w3p, b3, out);
}

// Round 13
// 42.498 us; speedup vs baseline: 1.2413x; 1.2413x over previous
//
#include <hip/hip_runtime.h>
#include <hip/hip_bf16.h>

// MLP_small_per_feature: per-feature MLP 1 -> 64 -> 64 -> 1, F=256, B=8192.
// v13 = v11 (best, 40.4us) with LAYER 1 MOVED TO MFMA (rank-2 trick):
//   h1 = w1 (x) x + b1 (x) 1  ==  mfma(A=[w1|b1] in k-slots 0/1, B=[x;1]).
//   A-rows packed with the SAME o' permutation as w2's outputs (v10-verified)
//   => layer-1's C/D lands in B-fragment k-slot order with k == h identity,
//   so relu+cvt_pk feeds layer-2's B directly and w2p/b2p/w3p packing is
//   UNCHANGED from v11. Removes layer-1's ~44 VALU/pass (fma+relu chains);
//   per-pass budget ~86 VALU + 10 MFMA -> ~55 VALU + 14 MFMA.
//   Cost: x rounds to bf16 (absmax expected ~0.06-0.09 vs threshold 0.1406).
//
// Dead ends proven: occupancy can't be raised (rounds 4/7/9/12: grid x4,
// LDS down, forced 512-thr stacking -> residency pinned ~2.5 waves/SIMD).
// Spill signatures: (256,8) -> VGPR=32 + 1.3GB scratch (v6); over-tight
// state -> SGPR=96, FETCH~=WRITE~=170MB (v5/v8). Canaries: SGPR<=48,
// WRITE~8MB.
//
// MFMA 16x16x32_bf16 layout (verified rounds 1-12):
//   A: row m = lane&15, k = (lane>>4)*8 + i
//   B: col n = lane&15, k = (lane>>4)*8 + i
//   C/D: col n = lane&15, row m = (lane>>4)*4 + r
//   o'(16t+m) = 32*(t>>1) + 8*(m>>2) + 4*(t&1) + (m&3)  [bijection 0..63]

namespace {

constexpr int kF = 256;
constexpr int kH = 64;
constexpr int kB = 8192;

constexpr int kFPB     = 4;               // features per block (one per wave)
constexpr int kRPB     = 128;             // rows per block
constexpr int kThreads = 256;             // 4 waves
constexpr int kFG      = kF / kFPB;       // 64 feature groups
constexpr int kRG      = kB / kRPB;       // 64 row groups
constexpr int kBlocks  = kFG * kRG;       // 4096
constexpr int kPasses  = kRPB / 16;       // 8
constexpr int kXP      = 10;              // xs pass-dim stride: conflict-free

using f32x2  = __attribute__((ext_vector_type(2))) float;
using f32x4  = __attribute__((ext_vector_type(4))) float;
using u32x4  = __attribute__((ext_vector_type(4))) unsigned;
using bf16x4 = __attribute__((ext_vector_type(4))) __bf16;
using bf16x8 = __attribute__((ext_vector_type(8))) __bf16;

// ---- prep: pack w2 (o'-out-permuted, bf16, fragment-major), b2
// (o'-permuted, C-order), w3 (bf16), and NEW w1b1p: dword per (t,m) =
// {bf16 w1[o'(16t+m)], bf16 b1[o'(16t+m)]} for the layer-1 A-fragments. ----
__global__ __launch_bounds__(256)
void pack_params(const float* __restrict__ w1, const float* __restrict__ b1,
                 const float* __restrict__ w2, const float* __restrict__ b2,
                 const float* __restrict__ w3, __bf16* __restrict__ w2p,
                 float* __restrict__ b2p, __bf16* __restrict__ w3p,
                 unsigned* __restrict__ w1b1p)
{
  const int wid  = (int)threadIdx.x >> 6;
  const int lane = (int)threadIdx.x & 63;
  const int f    = (int)blockIdx.x * 4 + wid;
  const int l15  = lane & 15;
  const int lg   = lane >> 4;

  const float* w2f = w2 + (size_t)f * (kH * kH);
  #pragma unroll
  for (int t = 0; t < 4; ++t) {
    const int o2 = 32 * (t >> 1) + 8 * (l15 >> 2) + 4 * (t & 1) + (l15 & 3);
    #pragma unroll
    for (int ks = 0; ks < 2; ++ks) {
      const float* p = w2f + o2 * kH + ks * 32 + lg * 8;
      const f32x4 lo = *reinterpret_cast<const f32x4*>(p);
      const f32x4 hi = *reinterpret_cast<const f32x4*>(p + 4);
      const bf16x8 v = __builtin_shufflevector(
          __builtin_convertvector(lo, bf16x4),
          __builtin_convertvector(hi, bf16x4), 0, 1, 2, 3, 4, 5, 6, 7);
      *reinterpret_cast<bf16x8*>(
          w2p + (((size_t)f * 8 + t * 2 + ks) * 64 + lane) * 8) = v;
    }
  }

  {
    const int jt = lane >> 4, jlg = (lane >> 2) & 3, jr = lane & 3;
    const int o  = 32 * (jt >> 1) + 8 * jlg + 4 * (jt & 1) + jr;
    b2p[(size_t)f * kH + lane] = b2[(size_t)f * kH + o];
  }
  w3p[(size_t)f * kH + lane] = (__bf16)w3[(size_t)f * kH + lane];

  {
    const int t = lane >> 4, m = lane & 15;
    const int o1 = 32 * (t >> 1) + 8 * (m >> 2) + 4 * (t & 1) + (m & 3);
    const __bf16 wv = (__bf16)w1[(size_t)f * kH + o1];
    const __bf16 bv = (__bf16)b1[(size_t)f * kH + o1];
    const unsigned u =
        (unsigned)__builtin_bit_cast(unsigned short, wv) |
        ((unsigned)__builtin_bit_cast(unsigned short, bv) << 16);
    w1b1p[(size_t)f * 64 + lane] = u;   // [f][t*16 + m]
  }
}

__global__ __launch_bounds__(kThreads, 3)
void mlp_pf_v13(const float* __restrict__ x,
                const __bf16* __restrict__ w2p,
                const float* __restrict__ b2p,
                const __bf16* __restrict__ w3p,
                const unsigned* __restrict__ w1b1p,
                const float* __restrict__ b3,
                float* __restrict__ out)
{
  __shared__ float xs[kFPB][16][kXP];     // 2.5 KB [feat][l15][pass]
  __shared__ float outb[kRPB][kFPB + 1];  // 2.56 KB (pad: conflict-free)

  const int tid  = (int)threadIdx.x;
  const int wid  = tid >> 6;
  const int lane = tid & 63;
  const int l15  = lane & 15;
  const int lg   = lane >> 4;

  const int fg = (int)blockIdx.x & (kFG - 1);  // consecutive blocks: same rows
  const int rg = (int)blockIdx.x >> 6;
  const int f  = fg * kFPB + wid;          // this wave's feature
  const int r0 = rg * kRPB;

  // ---- w2 fragments: 8 coalesced 16B loads/lane (L2-resident w2p) ----
  bf16x8 w2frag[4][2];
  {
    const __bf16* base = w2p + ((size_t)f * 8 * 64 + lane) * 8;
    #pragma unroll
    for (int t = 0; t < 4; ++t)
      #pragma unroll
      for (int ks = 0; ks < 2; ++ks)
        w2frag[t][ks] = *reinterpret_cast<const bf16x8*>(
            base + (size_t)(t * 2 + ks) * 64 * 8);
  }

  // ---- stage x tile (128 rows x 4 feats) -> pass-major LDS ----
  if (tid < kRPB) {
    const int rr = tid;
    const f32x4 v = *reinterpret_cast<const f32x4*>(
        x + (size_t)(r0 + rr) * kF + fg * kFPB);
    const int a = rr & 15, b = rr >> 4;
    xs[0][a][b] = v[0]; xs[1][a][b] = v[1];
    xs[2][a][b] = v[2]; xs[3][a][b] = v[3];
  }

  // ---- layer-1 A-fragments: {w1,b1} in k-slots 0/1 (lg==0 lanes only) ----
  bf16x8 w1b1f[4];
  {
    const unsigned* wb = w1b1p + (size_t)f * 64;
    #pragma unroll
    for (int t = 0; t < 4; ++t) {
      unsigned u = wb[t * 16 + l15];
      u = (lg == 0) ? u : 0u;
      const u32x4 q = {u, 0u, 0u, 0u};
      w1b1f[t] = __builtin_bit_cast(bf16x8, q);
    }
  }

  // ---- remaining per-wave params ----
  f32x4 b2c[4];
  #pragma unroll
  for (int t = 0; t < 4; ++t)
    b2c[t] = *reinterpret_cast<const f32x4*>(b2p + f * kH + t * 16 + lg * 4);
  bf16x8 w3f[2];
  #pragma unroll
  for (int ks = 0; ks < 2; ++ks)
    w3f[ks] = *reinterpret_cast<const bf16x8*>(w3p + f * kH + ks * 32 + lg * 8);
  const float b3v = b3[f];
  const f32x4 b3c = {b3v, b3v, b3v, b3v};

  __syncthreads();   // xs ready

  const f32x4 zero4 = {0.f, 0.f, 0.f, 0.f};
  float keep = 0.f;

  // B-operand for layer 1: {bf16(x), 1.0bf16, 0 x6} on lg==0 lanes, else 0
  auto make_xb = [&](float xvf) -> bf16x8 {
    unsigned u =
        (unsigned)__builtin_bit_cast(unsigned short, (__bf16)xvf) | 0x3F800000u;
    u = (lg == 0) ? u : 0u;
    const u32x4 q = {u, 0u, 0u, 0u};
    return __builtin_bit_cast(bf16x8, q);
  };
  // relu + pack two f32x4 C/D quads into one bf16 B-fragment
  auto pack2 = [&](const f32x4& a, const f32x4& b) -> bf16x8 {
    return __builtin_shufflevector(
        __builtin_convertvector(__builtin_elementwise_max(a, zero4), bf16x4),
        __builtin_convertvector(__builtin_elementwise_max(b, zero4), bf16x4),
        0, 1, 2, 3, 4, 5, 6, 7);
  };

  #pragma unroll
  for (int pp = 0; pp < kPasses / 2; ++pp) {
    // both passes' x values in one conflict-free ds_read_b64
    const f32x2 xp = *reinterpret_cast<const f32x2*>(&xs[wid][l15][2 * pp]);
    const bf16x8 xbA = make_xb(xp[0]);
    const bf16x8 xbB = make_xb(xp[1]);

    // ---- layer 1 via MFMA: D = w1 (x) x + b1 (x) 1, o'-permuted rows ----
    f32x4 a1A[4], a1B[4];
    #pragma unroll
    for (int t = 0; t < 4; ++t) {
      a1A[t] = __builtin_amdgcn_mfma_f32_16x16x32_bf16(
          w1b1f[t], xbA, zero4, 0, 0, 0);
      a1B[t] = __builtin_amdgcn_mfma_f32_16x16x32_bf16(
          w1b1f[t], xbB, zero4, 0, 0, 0);
    }

    // ---- relu + cvt: h1 B-fragments (k == h identity by o' packing) ----
    const bf16x8 h1A0 = pack2(a1A[0], a1A[1]);
    const bf16x8 h1A1 = pack2(a1A[2], a1A[3]);
    const bf16x8 h1B0 = pack2(a1B[0], a1B[1]);
    const bf16x8 h1B1 = pack2(a1B[2], a1B[3]);

    // ---- layer 2 (C = o'-permuted b2), A/B interleaved ----
    f32x4 accA[4], accB[4];
    #pragma unroll
    for (int t = 0; t < 4; ++t) {
      accA[t] = __builtin_amdgcn_mfma_f32_16x16x32_bf16(
          w2frag[t][0], h1A0, b2c[t], 0, 0, 0);
      accB[t] = __builtin_amdgcn_mfma_f32_16x16x32_bf16(
          w2frag[t][0], h1B0, b2c[t], 0, 0, 0);
      accA[t] = __builtin_amdgcn_mfma_f32_16x16x32_bf16(
          w2frag[t][1], h1A1, accA[t], 0, 0, 0);
      accB[t] = __builtin_amdgcn_mfma_f32_16x16x32_bf16(
          w2frag[t][1], h1B1, accB[t], 0, 0, 0);
    }

    // ---- relu + cvt: h2 B-fragments ----
    const bf16x8 h2A0 = pack2(accA[0], accA[1]);
    const bf16x8 h2A1 = pack2(accA[2], accA[3]);
    const bf16x8 h2B0 = pack2(accB[0], accB[1]);
    const bf16x8 h2B1 = pack2(accB[2], accB[3]);

    // ---- layer 3 via MFMA (C = b3 splat) ----
    f32x4 dA = __builtin_amdgcn_mfma_f32_16x16x32_bf16(w3f[0], h2A0, b3c, 0, 0, 0);
    f32x4 dB = __builtin_amdgcn_mfma_f32_16x16x32_bf16(w3f[0], h2B0, b3c, 0, 0, 0);
    dA = __builtin_amdgcn_mfma_f32_16x16x32_bf16(w3f[1], h2A1, dA, 0, 0, 0);
    dB = __builtin_amdgcn_mfma_f32_16x16x32_bf16(w3f[1], h2B1, dB, 0, 0, 0);

    // ---- keep-trick: lane-group lg keeps pass quad*4+lg ----
    const int pA = 2 * pp, pB = 2 * pp + 1;
    keep = (lg == (pA & 3)) ? dA[0] : keep;
    keep = (lg == (pB & 3)) ? dB[0] : keep;
    if ((pB & 3) == 3) {
      outb[(pB >> 2) * 64 + lane][wid] = keep;   // b3 already folded in
    }
  }

  __syncthreads();

  // ---- output: one float4 (4 features) per row ----
  if (tid < kRPB) {
    const int rr = tid;
    const f32x4 v = {outb[rr][0], outb[rr][1], outb[rr][2], outb[rr][3]};
    *reinterpret_cast<f32x4*>(out + (size_t)(r0 + rr) * kF + fg * kFPB) = v;
  }
}

}  // namespace

extern "C" void kernel_launch(void* const* d_in, const int* in_sizes, int n_in,
                              void* d_out, int out_size, void* d_ws, size_t ws_size,
                              hipStream_t stream) {
  const float* x  = (const float*)d_in[0];
  const float* w1 = (const float*)d_in[1];
  const float* b1 = (const float*)d_in[2];
  const float* w2 = (const float*)d_in[3];
  const float* b2 = (const float*)d_in[4];
  const float* w3 = (const float*)d_in[5];
  const float* b3 = (const float*)d_in[6];
  float* out = (float*)d_out;

  __bf16*   w2p   = (__bf16*)d_ws;                                    // 2 MB
  float*    b2p   = (float*)((char*)d_ws + (2u << 20));               // 64 KB
  __bf16*   w3p   = (__bf16*)((char*)d_ws + (2u << 20) + (64u << 10));// 32 KB
  unsigned* w1b1p = (unsigned*)((char*)d_ws + (2u << 20) + (96u << 10)); // 64 KB

  hipLaunchKernelGGL(pack_params, dim3(kF / 4), dim3(256), 0, stream,
                     w1, b1, w2, b2, w3, w2p, b2p, w3p, w1b1p);
  hipLaunchKernelGGL(mlp_pf_v13, dim3(kBlocks), dim3(kThreads), 0, stream,
                     x, w2p, b2p, w3p, w1b1p, b3, out);
}

// Round 14
// 40.591 us; speedup vs baseline: 1.2996x; 1.0470x over previous
//
#include <hip/hip_runtime.h>
#include <hip/hip_bf16.h>

// MLP_small_per_feature: per-feature MLP 1 -> 64 -> 64 -> 1, F=256, B=8192.
// v14 = v11 (best, 40.4us; absmax 0.03125) + intra-wave software pipeline:
//   - all 8 x values preloaded to regs via 2x ds_read_b128 (kXP=12: aligned,
//     2-way banks = free); the pass loop has ZERO LDS reads.
//   - 4-stage manual pipeline: layer-1 VALU of pair i+1 is issued BEFORE the
//     MFMA block of pair i (independent chains; VALU and MFMA pipes overlap
//     per m114). v11 serialized these phases within a wave.
//   - launch_bounds(256,3): worst case the allocator re-serializes (=v11).
// Carried verified pieces: o'-permuted w2p (layer2 C/D lands in B-fragment
// k-slot order), epilogue layer-3 MFMA w/ b3-in-C, b2-in-C, keep-trick
// store, outb exchange, pack kernel (w2p/b2p/w3p).
//
// Dead ends proven: occupancy unraisable (rounds 4/7/9/12); layer1-as-MFMA
// regresses (v13: serial MFMA chain); spill signatures (v5/v6/v8): VGPR=32
// or SGPR=96 + FETCH~=WRITE~=170MB. Canaries: SGPR<=48, WRITE~8MB.
//
// MFMA 16x16x32_bf16 layout (verified rounds 1-13):
//   A: row m = lane&15, k = (lane>>4)*8 + i
//   B: col n = lane&15, k = (lane>>4)*8 + i
//   C/D: col n = lane&15, row m = (lane>>4)*4 + r
//   o'(16t+m) = 32*(t>>1) + 8*(m>>2) + 4*(t&1) + (m&3)

namespace {

constexpr int kF = 256;
constexpr int kH = 64;
constexpr int kB = 8192;

constexpr int kFPB     = 4;               // features per block (one per wave)
constexpr int kRPB     = 128;             // rows per block
constexpr int kThreads = 256;             // 4 waves
constexpr int kFG      = kF / kFPB;       // 64 feature groups
constexpr int kRG      = kB / kRPB;       // 64 row groups
constexpr int kBlocks  = kFG * kRG;       // 4096
constexpr int kXP      = 12;              // pass-dim stride: 16B-aligned, 2-way banks

using f32x4  = __attribute__((ext_vector_type(4))) float;
using bf16x4 = __attribute__((ext_vector_type(4))) __bf16;
using bf16x8 = __attribute__((ext_vector_type(8))) __bf16;

// ---- prep: pack w2 (o'-out-permuted, bf16, fragment-major), b2
// (o'-permuted, C-order), w3 (bf16). Verified v10-v13. ----
__global__ __launch_bounds__(256)
void pack_params(const float* __restrict__ w2, const float* __restrict__ b2,
                 const float* __restrict__ w3, __bf16* __restrict__ w2p,
                 float* __restrict__ b2p, __bf16* __restrict__ w3p)
{
  const int wid  = (int)threadIdx.x >> 6;
  const int lane = (int)threadIdx.x & 63;
  const int f    = (int)blockIdx.x * 4 + wid;
  const int l15  = lane & 15;
  const int lg   = lane >> 4;

  const float* w2f = w2 + (size_t)f * (kH * kH);
  #pragma unroll
  for (int t = 0; t < 4; ++t) {
    const int o2 = 32 * (t >> 1) + 8 * (l15 >> 2) + 4 * (t & 1) + (l15 & 3);
    #pragma unroll
    for (int ks = 0; ks < 2; ++ks) {
      const float* p = w2f + o2 * kH + ks * 32 + lg * 8;
      const f32x4 lo = *reinterpret_cast<const f32x4*>(p);
      const f32x4 hi = *reinterpret_cast<const f32x4*>(p + 4);
      const bf16x8 v = __builtin_shufflevector(
          __builtin_convertvector(lo, bf16x4),
          __builtin_convertvector(hi, bf16x4), 0, 1, 2, 3, 4, 5, 6, 7);
      *reinterpret_cast<bf16x8*>(
          w2p + (((size_t)f * 8 + t * 2 + ks) * 64 + lane) * 8) = v;
    }
  }

  {
    const int jt = lane >> 4, jlg = (lane >> 2) & 3, jr = lane & 3;
    const int o  = 32 * (jt >> 1) + 8 * jlg + 4 * (jt & 1) + jr;
    b2p[(size_t)f * kH + lane] = b2[(size_t)f * kH + o];
  }
  w3p[(size_t)f * kH + lane] = (__bf16)w3[(size_t)f * kH + lane];
}

__global__ __launch_bounds__(kThreads, 3)
void mlp_pf_v14(const float* __restrict__ x,
                const float* __restrict__ w1,
                const float* __restrict__ b1,
                const __bf16* __restrict__ w2p,
                const float* __restrict__ b2p,
                const __bf16* __restrict__ w3p,
                const float* __restrict__ b3,
                float* __restrict__ out)
{
  __shared__ float xs[kFPB][16][kXP];     // 3 KB [feat][l15][pass]
  __shared__ float outb[kRPB][kFPB + 1];  // 2.56 KB (pad: conflict-free)

  const int tid  = (int)threadIdx.x;
  const int wid  = tid >> 6;
  const int lane = tid & 63;
  const int l15  = lane & 15;
  const int lg   = lane >> 4;

  const int fg = (int)blockIdx.x & (kFG - 1);  // consecutive blocks: same rows
  const int rg = (int)blockIdx.x >> 6;
  const int f  = fg * kFPB + wid;          // this wave's feature
  const int r0 = rg * kRPB;

  // ---- w2 fragments: 8 coalesced 16B loads/lane (L2-resident w2p) ----
  bf16x8 w2frag[4][2];
  {
    const __bf16* base = w2p + ((size_t)f * 8 * 64 + lane) * 8;
    #pragma unroll
    for (int t = 0; t < 4; ++t)
      #pragma unroll
      for (int ks = 0; ks < 2; ++ks)
        w2frag[t][ks] = *reinterpret_cast<const bf16x8*>(
            base + (size_t)(t * 2 + ks) * 64 * 8);
  }

  // ---- stage x tile (128 rows x 4 feats) -> pass-major LDS ----
  if (tid < kRPB) {
    const int rr = tid;
    const f32x4 v = *reinterpret_cast<const f32x4*>(
        x + (size_t)(r0 + rr) * kF + fg * kFPB);
    const int a = rr & 15, b = rr >> 4;
    xs[0][a][b] = v[0]; xs[1][a][b] = v[1];
    xs[2][a][b] = v[2]; xs[3][a][b] = v[3];
  }

  // ---- per-wave params ----
  f32x4 w1v[2][2], b1v[2][2];
  #pragma unroll
  for (int ks = 0; ks < 2; ++ks) {
    const float* pw = w1 + f * kH + ks * 32 + lg * 8;
    const float* pb = b1 + f * kH + ks * 32 + lg * 8;
    w1v[ks][0] = *reinterpret_cast<const f32x4*>(pw);
    w1v[ks][1] = *reinterpret_cast<const f32x4*>(pw + 4);
    b1v[ks][0] = *reinterpret_cast<const f32x4*>(pb);
    b1v[ks][1] = *reinterpret_cast<const f32x4*>(pb + 4);
  }
  f32x4 b2c[4];
  #pragma unroll
  for (int t = 0; t < 4; ++t)
    b2c[t] = *reinterpret_cast<const f32x4*>(b2p + f * kH + t * 16 + lg * 4);
  bf16x8 w3f[2];
  #pragma unroll
  for (int ks = 0; ks < 2; ++ks)
    w3f[ks] = *reinterpret_cast<const bf16x8*>(w3p + f * kH + ks * 32 + lg * 8);
  const float b3v = b3[f];
  const f32x4 b3c = {b3v, b3v, b3v, b3v};

  __syncthreads();   // xs ready

  // ---- all 8 x values -> registers (2 conflict-free ds_read_b128) ----
  const f32x4 xq0 = *reinterpret_cast<const f32x4*>(&xs[wid][l15][0]);
  const f32x4 xq1 = *reinterpret_cast<const f32x4*>(&xs[wid][l15][4]);

  const f32x4 zero4 = {0.f, 0.f, 0.f, 0.f};
  float keep = 0.f;

  struct PairH1 { bf16x8 a0, a1, b0, b1; };

  // layer-1 VALU for pass-pair (xa, xb) -> 4 bf16 B-fragments
  auto mk = [&](float xa, float xb) -> PairH1 {
    PairH1 r;
    #pragma unroll
    for (int ks = 0; ks < 2; ++ks) {
      f32x4 aA = w1v[ks][0] * xa + b1v[ks][0];
      f32x4 bA = w1v[ks][1] * xa + b1v[ks][1];
      f32x4 aB = w1v[ks][0] * xb + b1v[ks][0];
      f32x4 bB = w1v[ks][1] * xb + b1v[ks][1];
      aA = __builtin_elementwise_max(aA, zero4);
      bA = __builtin_elementwise_max(bA, zero4);
      aB = __builtin_elementwise_max(aB, zero4);
      bB = __builtin_elementwise_max(bB, zero4);
      const bf16x8 hA = __builtin_shufflevector(
          __builtin_convertvector(aA, bf16x4),
          __builtin_convertvector(bA, bf16x4), 0, 1, 2, 3, 4, 5, 6, 7);
      const bf16x8 hB = __builtin_shufflevector(
          __builtin_convertvector(aB, bf16x4),
          __builtin_convertvector(bB, bf16x4), 0, 1, 2, 3, 4, 5, 6, 7);
      if (ks == 0) { r.a0 = hA; r.b0 = hB; } else { r.a1 = hA; r.b1 = hB; }
    }
    return r;
  };

  auto pack2 = [&](const f32x4& a, const f32x4& b) -> bf16x8 {
    return __builtin_shufflevector(
        __builtin_convertvector(__builtin_elementwise_max(a, zero4), bf16x4),
        __builtin_convertvector(__builtin_elementwise_max(b, zero4), bf16x4),
        0, 1, 2, 3, 4, 5, 6, 7);
  };

  // MFMA block + store for pair i (passes 2i, 2i+1); PI is compile-time
  auto fin = [&](const PairH1& h, int PI) {
    f32x4 accA[4], accB[4];
    #pragma unroll
    for (int t = 0; t < 4; ++t) {
      accA[t] = __builtin_amdgcn_mfma_f32_16x16x32_bf16(
          w2frag[t][0], h.a0, b2c[t], 0, 0, 0);
      accB[t] = __builtin_amdgcn_mfma_f32_16x16x32_bf16(
          w2frag[t][0], h.b0, b2c[t], 0, 0, 0);
      accA[t] = __builtin_amdgcn_mfma_f32_16x16x32_bf16(
          w2frag[t][1], h.a1, accA[t], 0, 0, 0);
      accB[t] = __builtin_amdgcn_mfma_f32_16x16x32_bf16(
          w2frag[t][1], h.b1, accB[t], 0, 0, 0);
    }
    const bf16x8 h2A0 = pack2(accA[0], accA[1]);
    const bf16x8 h2A1 = pack2(accA[2], accA[3]);
    const bf16x8 h2B0 = pack2(accB[0], accB[1]);
    const bf16x8 h2B1 = pack2(accB[2], accB[3]);

    f32x4 dA = __builtin_amdgcn_mfma_f32_16x16x32_bf16(w3f[0], h2A0, b3c, 0, 0, 0);
    f32x4 dB = __builtin_amdgcn_mfma_f32_16x16x32_bf16(w3f[0], h2B0, b3c, 0, 0, 0);
    dA = __builtin_amdgcn_mfma_f32_16x16x32_bf16(w3f[1], h2A1, dA, 0, 0, 0);
    dB = __builtin_amdgcn_mfma_f32_16x16x32_bf16(w3f[1], h2B1, dB, 0, 0, 0);

    const int pA = 2 * PI, pB = 2 * PI + 1;
    keep = (lg == (pA & 3)) ? dA[0] : keep;
    keep = (lg == (pB & 3)) ? dB[0] : keep;
    if ((pB & 3) == 3) {
      outb[(pB >> 2) * 64 + lane][wid] = keep;   // b3 folded in
    }
  };

  // ---- 4-stage pipeline: mk(i+1) issued before fin(i) ----
  PairH1 c  = mk(xq0[0], xq0[1]);
  PairH1 n1 = mk(xq0[2], xq0[3]);
  fin(c, 0);
  PairH1 n2 = mk(xq1[0], xq1[1]);
  fin(n1, 1);
  PairH1 n3 = mk(xq1[2], xq1[3]);
  fin(n2, 2);
  fin(n3, 3);

  __syncthreads();

  // ---- output: one float4 (4 features) per row ----
  if (tid < kRPB) {
    const int rr = tid;
    const f32x4 v = {outb[rr][0], outb[rr][1], outb[rr][2], outb[rr][3]};
    *reinterpret_cast<f32x4*>(out + (size_t)(r0 + rr) * kF + fg * kFPB) = v;
  }
}

}  // namespace

extern "C" void kernel_launch(void* const* d_in, const int* in_sizes, int n_in,
                              void* d_out, int out_size, void* d_ws, size_t ws_size,
                              hipStream_t stream) {
  const float* x  = (const float*)d_in[0];
  const float* w1 = (const float*)d_in[1];
  const float* b1 = (const float*)d_in[2];
  const float* w2 = (const float*)d_in[3];
  const float* b2 = (const float*)d_in[4];
  const float* w3 = (const float*)d_in[5];
  const float* b3 = (const float*)d_in[6];
  float* out = (float*)d_out;

  __bf16* w2p = (__bf16*)d_ws;                           // 2 MB
  float*  b2p = (float*)((char*)d_ws + (2u << 20));      // 64 KB
  __bf16* w3p = (__bf16*)((char*)d_ws + (2u << 20) + (64u << 10));  // 32 KB

  hipLaunchKernelGGL(pack_params, dim3(kF / 4), dim3(256), 0, stream,
                     w2, b2, w3, w2p, b2p, w3p);
  hipLaunchKernelGGL(mlp_pf_v14, dim3(kBlocks), dim3(kThreads), 0, stream,
                     x, w1, b1, w2p, b2p, w3p, b3, out);
}